// Round 1
// baseline (97.949 us; speedup 1.0000x reference)
//
#include <hip/hip_runtime.h>
#include <math.h>

// Problem: out[0] = (1 - mean(Y)) + 5e-5 / sqrt(min_d2)
//   min_d2 = min over b in [0,64), pairs n<m in [0,1024) of
//            (sq_n + sq_m) - 2*(xn*xm + yn*ym), excluding values <= 0.
// Points: (x[b, 20k], x[b, 20k+1]), k = 0..1023.
//
// CRITICAL: float32 rounding must match the reference exactly (min is
// noise-dominated: true min ~1e-7, cancellation noise ~3e-7). Use
// __fmul_rn/__fadd_rn/__fsub_rn to forbid FMA contraction and reproduce
//   e  = rn(rn(xn*xm) + rn(yn*ym))
//   t  = rn(sq_n + sq_m)
//   d2 = rn(t - 2*e)          // 2*e is exact (power-of-2 scale)
// This expression is symmetric in (n,m) (IEEE add/mul commutative), so the
// circulant enumeration m=(n+k)&1023, k=1..511 (+k=512 for n<512) covers
// each unordered pair exactly once with perfect load balance.

#define NPTS   1024
#define XCOLS  20480
#define PSTRIDE 20

__global__ __launch_bounds__(256) void pair_min_kernel(const float* __restrict__ x,
                                                       float* __restrict__ block_min) {
    __shared__ float2 pts[NPTS];
    __shared__ float  sqv[NPTS];

    const int b   = blockIdx.x >> 2;   // batch (4 blocks per batch)
    const int q   = blockIdx.x & 3;    // quadrant
    const int tid = threadIdx.x;

    const float* xb = x + (size_t)b * XCOLS;
    for (int i = tid; i < NPTS; i += 256) {
        // offsets 20i, 20i+1 are adjacent; byte addr 80*i is 8B-aligned
        float2 p = *reinterpret_cast<const float2*>(xb + i * PSTRIDE);
        pts[i] = p;
        sqv[i] = __fadd_rn(__fmul_rn(p.x, p.x), __fmul_rn(p.y, p.y));
    }
    __syncthreads();

    const int    n   = q * 256 + tid;  // this thread's point
    const float2 pn  = pts[n];
    const float  sqn = sqv[n];
    const float  INF = __int_as_float(0x7f800000);

    float lmin = INF;
    #pragma unroll 4
    for (int k = 1; k <= 511; ++k) {
        const int    m  = (n + k) & (NPTS - 1);
        const float2 pm = pts[m];
        const float  sm = sqv[m];
        const float  e  = __fadd_rn(__fmul_rn(pn.x, pm.x), __fmul_rn(pn.y, pm.y));
        const float  t  = __fadd_rn(sqn, sm);
        const float  d2 = __fsub_rn(t, __fmul_rn(2.0f, e));
        lmin = fminf(lmin, d2 > 0.0f ? d2 : INF);
    }
    if (n < 512) {  // the k=512 diagonal, counted once
        const int    m  = n + 512;
        const float2 pm = pts[m];
        const float  sm = sqv[m];
        const float  e  = __fadd_rn(__fmul_rn(pn.x, pm.x), __fmul_rn(pn.y, pm.y));
        const float  t  = __fadd_rn(sqn, sm);
        const float  d2 = __fsub_rn(t, __fmul_rn(2.0f, e));
        lmin = fminf(lmin, d2 > 0.0f ? d2 : INF);
    }

    // wave (64-lane) min reduce
    #pragma unroll
    for (int off = 32; off >= 1; off >>= 1)
        lmin = fminf(lmin, __shfl_xor(lmin, off, 64));

    __shared__ float wmins[4];
    if ((tid & 63) == 0) wmins[tid >> 6] = lmin;
    __syncthreads();
    if (tid == 0) {
        block_min[blockIdx.x] = fminf(fminf(wmins[0], wmins[1]),
                                      fminf(wmins[2], wmins[3]));
    }
}

__global__ __launch_bounds__(256) void finalize_kernel(const float* __restrict__ block_min,
                                                       const float* __restrict__ Y,
                                                       float* __restrict__ out) {
    const int tid = threadIdx.x;

    // min over the 256 block minima
    float v = block_min[tid];
    #pragma unroll
    for (int off = 32; off >= 1; off >>= 1)
        v = fminf(v, __shfl_xor(v, off, 64));

    __shared__ float wmins[4];
    __shared__ float ysum_s;
    if ((tid & 63) == 0) wmins[tid >> 6] = v;

    // sum of Y (64 values) in wave 0
    float ys = (tid < 64) ? Y[tid] : 0.0f;
    #pragma unroll
    for (int off = 32; off >= 1; off >>= 1)
        ys += __shfl_xor(ys, off, 64);
    if (tid == 0) ysum_s = ys;
    __syncthreads();

    if (tid == 0) {
        const float minv = fminf(fminf(wmins[0], wmins[1]),
                                 fminf(wmins[2], wmins[3]));
        const float sr   = 1.0f - ysum_s * (1.0f / 64.0f);
        const float reg  = 5e-5f / __fsqrt_rn(minv);
        out[0] = sr + reg;
    }
}

extern "C" void kernel_launch(void* const* d_in, const int* in_sizes, int n_in,
                              void* d_out, int out_size, void* d_ws, size_t ws_size,
                              hipStream_t stream) {
    const float* x = (const float*)d_in[0];   // (64, 20480) f32
    const float* Y = (const float*)d_in[1];   // (64, 1)     f32
    float* out  = (float*)d_out;              // scalar f32
    float* bmin = (float*)d_ws;               // 256 floats of scratch

    pair_min_kernel<<<dim3(256), dim3(256), 0, stream>>>(x, bmin);
    finalize_kernel<<<dim3(1), dim3(256), 0, stream>>>(bmin, Y, out);
}

// Round 3
// 68.467 us; speedup vs baseline: 1.4306x; 1.4306x over previous
//
#include <hip/hip_runtime.h>
#include <math.h>

// out[0] = (1 - mean(Y)) + 5e-5 / sqrt(min_d2), min over 64 batches x all
// unordered pairs of 1024 2-D points (x[b,20k], x[b,20k+1]).
//
// Rounding must be bit-exact vs numpy reference (min is cancellation-noise
// dominated): d2 = rn(rn(sq_n+sq_m) - rn(2*rn(rn(xn*xm)+rn(yn*ym)))).
// Verified absmax 0.0 in round 1 with identical per-pair expression.
//
// Enumeration: circulant m=(n+k)&1023, k=1..511 all n, k=512 only n<512.
// Thread tile: 4 consecutive n per thread -> partners at shift k are also
// consecutive -> sliding window, 1 new LDS element per k serves 4 pairs.
// LDS layout transposed: slot(j) = ((j&3)<<8)|(j>>2) so consecutive lanes
// (n0=4*tid) read consecutive slots -> conflict-free.

#define NPTS    1024
#define XCOLS   20480
#define PSTRIDE 20
#define BPB     16              // blocks per batch
#define KRANGE  32              // 512 / BPB k-values per block
#define NBLOCKS (64 * BPB)      // 1024

__device__ __forceinline__ int lds_slot(int j) {
    return ((j & 3) << 8) | (j >> 2);
}

__global__ __launch_bounds__(256) void pair_min_kernel(const float* __restrict__ x,
                                                       float* __restrict__ block_min) {
    __shared__ float2 pts[NPTS];
    __shared__ float  sqv[NPTS];

    const int b   = blockIdx.x >> 4;        // batch
    const int q   = blockIdx.x & (BPB - 1); // k-slice
    const int tid = threadIdx.x;

    const float* xb = x + (size_t)b * XCOLS;
    #pragma unroll
    for (int i0 = 0; i0 < NPTS; i0 += 256) {
        const int i = i0 + tid;
        float2 p = *reinterpret_cast<const float2*>(xb + i * PSTRIDE);
        const int s = lds_slot(i);
        pts[s] = p;
        sqv[s] = __fadd_rn(__fmul_rn(p.x, p.x), __fmul_rn(p.y, p.y));
    }
    __syncthreads();

    const int n0 = tid << 2;
    float2 pn0, pn1, pn2, pn3;
    float  q0, q1, q2, q3;
    {
        int s;
        s = (0 << 8) | tid; pn0 = pts[s]; q0 = sqv[s];
        s = (1 << 8) | tid; pn1 = pts[s]; q1 = sqv[s];
        s = (2 << 8) | tid; pn2 = pts[s]; q2 = sqv[s];
        s = (3 << 8) | tid; pn3 = pts[s]; q3 = sqv[s];
    }

    const float INF = __int_as_float(0x7f800000);
    const int kstart = q * KRANGE + 1;

    // window: at iteration k, w0..w2 hold points (n0+k)..(n0+k+2)
    float2 w0, w1, w2, w3;
    float  s0, s1, s2, s3;
    {
        int j, s;
        j = (n0 + kstart    ) & (NPTS - 1); s = lds_slot(j); w0 = pts[s]; s0 = sqv[s];
        j = (n0 + kstart + 1) & (NPTS - 1); s = lds_slot(j); w1 = pts[s]; s1 = sqv[s];
        j = (n0 + kstart + 2) & (NPTS - 1); s = lds_slot(j); w2 = pts[s]; s2 = sqv[s];
    }

    float lmin = INF;

#define PAIR(PN, QN, W, SW, EXTRA)                                             \
    {                                                                          \
        const float e  = __fadd_rn(__fmul_rn((PN).x, (W).x),                   \
                                   __fmul_rn((PN).y, (W).y));                  \
        const float t  = __fadd_rn((QN), (SW));                                \
        const float d2 = __fsub_rn(t, __fmul_rn(2.0f, e));                     \
        lmin = fminf(lmin, (d2 > 0.0f EXTRA) ? d2 : INF);                      \
    }

    #pragma unroll 4
    for (int k = kstart; k < kstart + KRANGE - 4; ++k) {
        const int j = (n0 + k + 3) & (NPTS - 1);
        const int s = lds_slot(j);
        w3 = pts[s]; s3 = sqv[s];
        PAIR(pn0, q0, w0, s0, )
        PAIR(pn1, q1, w1, s1, )
        PAIR(pn2, q2, w2, s2, )
        PAIR(pn3, q3, w3, s3, )
        w0 = w1; s0 = s1;
        w1 = w2; s1 = s2;
        w2 = w3; s2 = s3;
    }

    // epilogue: last 4 k's; k==512 only counts pairs with n < 512
    #pragma unroll
    for (int k = kstart + KRANGE - 4; k < kstart + KRANGE; ++k) {
        const int j = (n0 + k + 3) & (NPTS - 1);
        const int s = lds_slot(j);
        w3 = pts[s]; s3 = sqv[s];
        const bool ok = (k <= 511) || (n0 < 512);
        PAIR(pn0, q0, w0, s0, && ok)
        PAIR(pn1, q1, w1, s1, && ok)
        PAIR(pn2, q2, w2, s2, && ok)
        PAIR(pn3, q3, w3, s3, && ok)
        w0 = w1; s0 = s1;
        w1 = w2; s1 = s2;
        w2 = w3; s2 = s3;
    }
#undef PAIR

    // wave (64-lane) min reduce
    #pragma unroll
    for (int off = 32; off >= 1; off >>= 1)
        lmin = fminf(lmin, __shfl_xor(lmin, off, 64));

    __shared__ float wmins[4];
    if ((tid & 63) == 0) wmins[tid >> 6] = lmin;
    __syncthreads();
    if (tid == 0) {
        block_min[blockIdx.x] = fminf(fminf(wmins[0], wmins[1]),
                                      fminf(wmins[2], wmins[3]));
    }
}

__global__ __launch_bounds__(256) void finalize_kernel(const float* __restrict__ block_min,
                                                       const float* __restrict__ Y,
                                                       float* __restrict__ out) {
    const int tid = threadIdx.x;

    // min over the 1024 block minima
    float v = block_min[tid];
    v = fminf(v, block_min[tid + 256]);
    v = fminf(v, block_min[tid + 512]);
    v = fminf(v, block_min[tid + 768]);
    #pragma unroll
    for (int off = 32; off >= 1; off >>= 1)
        v = fminf(v, __shfl_xor(v, off, 64));

    __shared__ float wmins[4];
    __shared__ float ysum_s;
    if ((tid & 63) == 0) wmins[tid >> 6] = v;

    // sum of Y (64 values) in wave 0
    float ys = (tid < 64) ? Y[tid] : 0.0f;
    #pragma unroll
    for (int off = 32; off >= 1; off >>= 1)
        ys += __shfl_xor(ys, off, 64);
    if (tid == 0) ysum_s = ys;
    __syncthreads();

    if (tid == 0) {
        const float minv = fminf(fminf(wmins[0], wmins[1]),
                                 fminf(wmins[2], wmins[3]));
        const float sr   = 1.0f - ysum_s * (1.0f / 64.0f);
        const float reg  = 5e-5f / __fsqrt_rn(minv);
        out[0] = sr + reg;
    }
}

extern "C" void kernel_launch(void* const* d_in, const int* in_sizes, int n_in,
                              void* d_out, int out_size, void* d_ws, size_t ws_size,
                              hipStream_t stream) {
    const float* x = (const float*)d_in[0];   // (64, 20480) f32
    const float* Y = (const float*)d_in[1];   // (64, 1)     f32
    float* out  = (float*)d_out;              // scalar f32
    float* bmin = (float*)d_ws;               // 1024 floats of scratch

    pair_min_kernel<<<dim3(NBLOCKS), dim3(256), 0, stream>>>(x, bmin);
    finalize_kernel<<<dim3(1), dim3(256), 0, stream>>>(bmin, Y, out);
}